// Round 17
// baseline (1744.541 us; speedup 1.0000x reference)
//
#include <hip/hip_runtime.h>
#include <math.h>
#include <stdint.h>

typedef int v4i  __attribute__((ext_vector_type(4)));
typedef int v16i __attribute__((ext_vector_type(16)));

#define NTOK 8192
#define HID  4096
#define FFND 14336

// K-tile counts (64-byte K-tiles) per matrix
#define KT1 (HID / 64)    // 64  : gemm1 K-dim
#define KT2 (FFND / 64)   // 224 : gemm2 K-dim

typedef const __attribute__((address_space(1))) void* gp_t;
typedef __attribute__((address_space(3))) void*       lp_t;

#define BAR()      __builtin_amdgcn_s_barrier()
#define SETPRIO(p) __builtin_amdgcn_s_setprio(p)
#define MEMFENCE() asm volatile("" ::: "memory")

// ============================================================================
// Tiled layout: matrix [R][C] int8 stored as 8KB tiles (rt,kt), rt over 128
// rows, kt over 64 k-bytes.  Tile base = ((size_t)rt*KT + kt)*8192.
// Within tile, byte (r,c): off = (c>>3)*1024 + r*8 + (c&7)   (K-major).
// A wave's 32-consecutive-row b64 read -> banks (2*row)%32 -> conflict-free.
// ============================================================================

__device__ __forceinline__ int pack4(int4 v) {
  return (v.x & 255) | ((v.y & 255) << 8) | ((v.z & 255) << 16) | ((v.w & 255) << 24);
}

// ---- prep: int32 weights [OUT][IN] -> tiled int8.  grid(ktiles*2, rtiles) ----
__global__ __launch_bounds__(256) void k_prep_w(
    const int* __restrict__ w32, int8_t* __restrict__ w8, int IN, int ktiles) {
  const int j  = blockIdx.x * 256 + threadIdx.x;   // int4 index within rt slice
  const int kt = j >> 9;
  const int q  = j & 511;
  const int hs = q >> 6;
  const int rp = (q & 63) << 1;                    // row pair base
  const int rt = blockIdx.y;
  const int* s0 = w32 + ((size_t)(rt * 128 + rp)) * IN + kt * 64 + hs * 8;
  const int* s1 = s0 + IN;
  int4 a0 = reinterpret_cast<const int4*>(s0)[0];
  int4 a1 = reinterpret_cast<const int4*>(s0)[1];
  int4 b0 = reinterpret_cast<const int4*>(s1)[0];
  int4 b1 = reinterpret_cast<const int4*>(s1)[1];
  int4 o;
  o.x = pack4(a0); o.y = pack4(a1); o.z = pack4(b0); o.w = pack4(b1);
  reinterpret_cast<int4*>(w8)[((size_t)rt * ktiles) * 512 + j] = o;
}

// ---- prep: fp32 x [T][HID] -> tiled int8 q1.  grid(KT1*2, T/128) ----
__global__ __launch_bounds__(256) void k_prep_x(
    const float* __restrict__ x, int8_t* __restrict__ qx,
    const float* __restrict__ a1sp) {
  const int j  = blockIdx.x * 256 + threadIdx.x;
  const int kt = j >> 9;
  const int q  = j & 511;
  const int hs = q >> 6;
  const int rp = (q & 63) << 1;
  const int rt = blockIdx.y;
  const float s = *a1sp;
  const float* s0 = x + ((size_t)(rt * 128 + rp)) * HID + kt * 64 + hs * 8;
  const float* s1 = s0 + HID;
  int w[4];
#pragma unroll
  for (int h = 0; h < 4; ++h) {
    const float* sp = (h < 2) ? s0 : s1;
    float4 f = reinterpret_cast<const float4*>(sp)[h & 1];
    int a = (int)rintf(f.x / s); a = a < -128 ? -128 : (a > 127 ? 127 : a);
    int b = (int)rintf(f.y / s); b = b < -128 ? -128 : (b > 127 ? 127 : b);
    int c = (int)rintf(f.z / s); c = c < -128 ? -128 : (c > 127 ? 127 : c);
    int d = (int)rintf(f.w / s); d = d < -128 ? -128 : (d > 127 ? 127 : d);
    w[h] = (a & 255) | ((b & 255) << 8) | ((c & 255) << 16) | ((d & 255) << 24);
  }
  int4 o; o.x = w[0]; o.y = w[1]; o.z = w[2]; o.w = w[3];
  reinterpret_cast<int4*>(qx)[((size_t)rt * KT1) * 512 + j] = o;
}

// ---- stage NSEG 1KB segments linearly (pre-tiled global -> LDS) ----
template <int NSEG, int NWAVES>
__device__ __forceinline__ void stage_lin(const int8_t* __restrict__ src,
                                          int8_t* lds, int wave, int lane) {
  constexpr int PER = NSEG / NWAVES;
#pragma unroll
  for (int j = 0; j < PER; ++j) {
    const int off = ((wave * PER + j) << 10) + (lane << 4);
    __builtin_amdgcn_global_load_lds((gp_t)(src + off), (lp_t)(lds + off), 16, 0, 0);
  }
}

// ---- read one MFMA fragment: row in [0,256), 16B k-slot ks in [0,4)
// two b64 at +0 / +1024 within the row's tile (conflict-free) ----
__device__ __forceinline__ v4i frag16T(const int8_t* lds, int row, int ks) {
  const int8_t* p = lds + ((row >> 7) << 13) + (ks << 11) + ((row & 127) << 3);
  const int2 lo = *reinterpret_cast<const int2*>(p);
  const int2 hi = *reinterpret_cast<const int2*>(p + 1024);
  v4i r; r[0] = lo.x; r[1] = lo.y; r[2] = hi.x; r[3] = hi.y;
  return r;
}

// ------- GEMM1 (champion schedule, tiled-LDS reads) -------
// 512 thr / 8 waves; tile 256x128 dual (gate+up); depth-3, 96 KiB, 1 block/CU.
// Per K-tile: vmcnt(4) -> BAR -> reads -> stage(kt+2) -> setprio MFMA.
__global__ __launch_bounds__(512, 2) void k_gemm1(
    const int8_t* __restrict__ q1, const int8_t* __restrict__ w1,
    const int8_t* __restrict__ w3, int8_t* __restrict__ q2,
    const float* __restrict__ w1sp, const float* __restrict__ w3sp,
    const float* __restrict__ a1sp, const float* __restrict__ a2sp) {
  __shared__ __align__(16) int8_t As[3][16384];   // 48 KiB (2 row-tiles each)
  __shared__ __align__(16) int8_t B1s[3][8192];   // 24 KiB
  __shared__ __align__(16) int8_t B3s[3][8192];   // 24 KiB
  const int lane = threadIdx.x & 63;
  const int wave = threadIdx.x >> 6;   // 0..7
  const int wr = wave >> 1;            // 0..3 (M quadrant, 64 rows)
  const int wc = wave & 1;             // 0..1 (N half, 64 cols)
  const int r0 = lane & 31;
  const int mbase = blockIdx.y * 256;
  const int nbase = blockIdx.x * 128;
  // tiled bases: tile(rt,kt) at (rt*KT + kt)*8192
  const int8_t* A0 = q1 + (size_t)(mbase >> 7)       * KT1 * 8192;  // rt0
  const int8_t* A1 = q1 + (size_t)((mbase >> 7) + 1) * KT1 * 8192;  // rt0+1
  const int8_t* B1p = w1 + (size_t)(nbase >> 7) * KT1 * 8192;
  const int8_t* B3p = w3 + (size_t)(nbase >> 7) * KT1 * 8192;
  constexpr int NT = KT1;

  v16i acc1[2][2], acc3[2][2];
#pragma unroll
  for (int m = 0; m < 2; ++m)
#pragma unroll
    for (int n = 0; n < 2; ++n)
#pragma unroll
      for (int r = 0; r < 16; ++r) { acc1[m][n][r] = 0; acc3[m][n][r] = 0; }

  // prologue: stage K-tiles 0,1 (4 loads/wave/tile, FIFO)
#pragma unroll
  for (int t = 0; t < 2; ++t) {
    stage_lin<8, 8>(A0  + t * 8192, As[t],        wave, lane);
    stage_lin<8, 8>(A1  + t * 8192, As[t] + 8192, wave, lane);
    stage_lin<8, 8>(B1p + t * 8192, B1s[t],       wave, lane);
    stage_lin<8, 8>(B3p + t * 8192, B3s[t],       wave, lane);
  }

  int cur = 0;
  for (int kt = 0; kt < NT; ++kt) {
    if (kt < NT - 1) asm volatile("s_waitcnt vmcnt(4)" ::: "memory");
    else             asm volatile("s_waitcnt vmcnt(0)" ::: "memory");
    BAR();
    MEMFENCE();
    const int8_t* Ac  = As[cur];
    const int8_t* B1c = B1s[cur];
    const int8_t* B3c = B3s[cur];
    v4i a[2][2], b1[2][2], b3[2][2];
#pragma unroll
    for (int kk = 0; kk < 2; ++kk) {
      const int ks = kk * 2 + (lane >> 5);
      a[kk][0]  = frag16T(Ac,  wr * 64 +      r0, ks);
      a[kk][1]  = frag16T(Ac,  wr * 64 + 32 + r0, ks);
      b1[kk][0] = frag16T(B1c, wc * 64 +      r0, ks);
      b1[kk][1] = frag16T(B1c, wc * 64 + 32 + r0, ks);
      b3[kk][0] = frag16T(B3c, wc * 64 +      r0, ks);
      b3[kk][1] = frag16T(B3c, wc * 64 + 32 + r0, ks);
    }
    const int nx2 = (cur >= 1) ? cur - 1 : 2;   // (kt+2)%3
    if (kt + 2 < NT) {
      stage_lin<8, 8>(A0  + (kt + 2) * 8192, As[nx2],        wave, lane);
      stage_lin<8, 8>(A1  + (kt + 2) * 8192, As[nx2] + 8192, wave, lane);
      stage_lin<8, 8>(B1p + (kt + 2) * 8192, B1s[nx2],       wave, lane);
      stage_lin<8, 8>(B3p + (kt + 2) * 8192, B3s[nx2],       wave, lane);
    }
    SETPRIO(1);
#pragma unroll
    for (int kk = 0; kk < 2; ++kk)
#pragma unroll
      for (int m = 0; m < 2; ++m)
#pragma unroll
        for (int n = 0; n < 2; ++n) {
          acc1[m][n] = __builtin_amdgcn_mfma_i32_32x32x32_i8(a[kk][m], b1[kk][n], acc1[m][n], 0, 0, 0);
          acc3[m][n] = __builtin_amdgcn_mfma_i32_32x32x32_i8(a[kk][m], b3[kk][n], acc3[m][n], 0, 0, 0);
        }
    SETPRIO(0);
    cur = (cur == 2) ? 0 : cur + 1;
  }

  const float s1 = (*a1sp) * (*w1sp);
  const float s3 = (*a1sp) * (*w3sp);
  const float ia2 = 1.f / (*a2sp);
#pragma unroll
  for (int m = 0; m < 2; ++m)
#pragma unroll
    for (int n = 0; n < 2; ++n) {
      const int colg = nbase + wc * 64 + n * 32 + r0;
      // tiled q2 column parts (constant over r)
      const size_t ct = (size_t)(colg >> 6) * 8192 + ((colg >> 3) & 7) * 1024 + (colg & 7);
#pragma unroll
      for (int r = 0; r < 16; ++r) {
        const int rowg = mbase + wr * 64 + m * 32 +
                         (r & 3) + ((r >> 2) << 3) + ((lane >> 5) << 2);
        const float g = (float)acc1[m][n][r] * s1;
        const float u = (float)acc3[m][n][r] * s3;
        const float h = g * __builtin_amdgcn_rcpf(1.f + __expf(-g)) * u;
        float t = rintf(h * ia2);
        t = fminf(fmaxf(t, -128.f), 127.f);
        q2[(size_t)(rowg >> 7) * KT2 * 8192 + ct + (rowg & 127) * 8] = (int8_t)(int)t;
      }
    }
}

// ------- GEMM2 (champion schedule: big-acc 1 wave/SIMD, tiled-LDS reads) -------
// 256 thr / 4 waves; block 256x256; per-wave 128x128 (acc 256 AGPR);
// depth-3 (96 KiB); vmcnt(8); reads -> stage -> setprio MFMA.
__global__ __launch_bounds__(256, 1) void k_gemm2(
    const int8_t* __restrict__ q2, const int8_t* __restrict__ w2,
    float* __restrict__ out,
    const float* __restrict__ w2sp, const float* __restrict__ a2sp) {
  __shared__ __align__(16) int8_t As[3][16384];  // 48 KiB
  __shared__ __align__(16) int8_t Bs[3][16384];  // 48 KiB
  const int lane = threadIdx.x & 63;
  const int wave = threadIdx.x >> 6;   // 0..3
  const int wr = wave >> 1;            // 0..1 (M half, 128 rows)
  const int wc = wave & 1;             // 0..1 (N half, 128 cols)
  const int r0 = lane & 31;
  const int mbase = blockIdx.y * 256;
  const int nbase = blockIdx.x * 256;
  const int8_t* A0 = q2 + (size_t)(mbase >> 7)       * KT2 * 8192;
  const int8_t* A1 = q2 + (size_t)((mbase >> 7) + 1) * KT2 * 8192;
  const int8_t* B0 = w2 + (size_t)(nbase >> 7)       * KT2 * 8192;
  const int8_t* B1 = w2 + (size_t)((nbase >> 7) + 1) * KT2 * 8192;
  constexpr int NT = KT2;

  v16i acc[4][4];
#pragma unroll
  for (int m = 0; m < 4; ++m)
#pragma unroll
    for (int n = 0; n < 4; ++n)
#pragma unroll
      for (int r = 0; r < 16; ++r) acc[m][n][r] = 0;

#pragma unroll
  for (int t = 0; t < 2; ++t) {
    stage_lin<8, 4>(A0 + t * 8192, As[t],        wave, lane);
    stage_lin<8, 4>(A1 + t * 8192, As[t] + 8192, wave, lane);
    stage_lin<8, 4>(B0 + t * 8192, Bs[t],        wave, lane);
    stage_lin<8, 4>(B1 + t * 8192, Bs[t] + 8192, wave, lane);
  }

  int cur = 0;
  for (int kt = 0; kt < NT; ++kt) {
    if (kt < NT - 1) asm volatile("s_waitcnt vmcnt(8)" ::: "memory");
    else             asm volatile("s_waitcnt vmcnt(0)" ::: "memory");
    BAR();
    MEMFENCE();
    const int8_t* Ac = As[cur];
    const int8_t* Bc = Bs[cur];
    v4i a[2][4], b[2][4];
#pragma unroll
    for (int kk = 0; kk < 2; ++kk) {
      const int ks = kk * 2 + (lane >> 5);
#pragma unroll
      for (int m = 0; m < 4; ++m)
        a[kk][m] = frag16T(Ac, wr * 128 + m * 32 + r0, ks);
#pragma unroll
      for (int n = 0; n < 4; ++n)
        b[kk][n] = frag16T(Bc, wc * 128 + n * 32 + r0, ks);
    }
    const int nx2 = (cur >= 1) ? cur - 1 : 2;
    if (kt + 2 < NT) {
      stage_lin<8, 4>(A0 + (kt + 2) * 8192, As[nx2],        wave, lane);
      stage_lin<8, 4>(A1 + (kt + 2) * 8192, As[nx2] + 8192, wave, lane);
      stage_lin<8, 4>(B0 + (kt + 2) * 8192, Bs[nx2],        wave, lane);
      stage_lin<8, 4>(B1 + (kt + 2) * 8192, Bs[nx2] + 8192, wave, lane);
    }
    SETPRIO(1);
#pragma unroll
    for (int kk = 0; kk < 2; ++kk)
#pragma unroll
      for (int m = 0; m < 4; ++m)
#pragma unroll
        for (int n = 0; n < 4; ++n)
          acc[m][n] = __builtin_amdgcn_mfma_i32_32x32x32_i8(a[kk][m], b[kk][n], acc[m][n], 0, 0, 0);
    SETPRIO(0);
    cur = (cur == 2) ? 0 : cur + 1;
  }

  const float s = (*a2sp) * (*w2sp);
#pragma unroll
  for (int m = 0; m < 4; ++m)
#pragma unroll
    for (int n = 0; n < 4; ++n) {
      const int colg = nbase + wc * 128 + n * 32 + r0;
#pragma unroll
      for (int r = 0; r < 16; ++r) {
        const int rowg = mbase + wr * 128 + m * 32 +
                         (r & 3) + ((r >> 2) << 3) + ((lane >> 5) << 2);
        out[(size_t)rowg * HID + colg] = (float)acc[m][n][r] * s;
      }
    }
}

extern "C" void kernel_launch(void* const* d_in, const int* in_sizes, int n_in,
                              void* d_out, int out_size, void* d_ws, size_t ws_size,
                              hipStream_t stream) {
  const float* x    = (const float*)d_in[0];
  const int*   w1i  = (const int*)d_in[1];   // int8 values stored as int32
  const int*   w3i  = (const int*)d_in[2];
  const int*   w2i  = (const int*)d_in[3];
  const float* w1s  = (const float*)d_in[4];
  const float* w3s  = (const float*)d_in[5];
  const float* w2s  = (const float*)d_in[6];
  const float* a1s  = (const float*)d_in[7];
  const float* a2s  = (const float*)d_in[8];
  float* out = (float*)d_out;

  // workspace layout (all tiled int8)
  int8_t* q1  = (int8_t*)d_ws;                         // [64][64] tiles   33.5 MB
  int8_t* q2  = q1 + (size_t)NTOK * HID;               // [64][224] tiles 117.4 MB
  int8_t* w1p = q2 + (size_t)NTOK * FFND;              // [112][64]        58.7 MB
  int8_t* w3p = w1p + (size_t)FFND * HID;              //                  58.7 MB
  int8_t* w2p = w3p + (size_t)FFND * HID;              // [32][224]        58.7 MB

  // prep: weights -> tiled int8; x -> tiled q1
  k_prep_w<<<dim3(KT1 * 2, FFND / 128), 256, 0, stream>>>(w1i, w1p, HID, KT1);
  k_prep_w<<<dim3(KT1 * 2, FFND / 128), 256, 0, stream>>>(w3i, w3p, HID, KT1);
  k_prep_w<<<dim3(KT2 * 2, HID / 128), 256, 0, stream>>>(w2i, w2p, FFND, KT2);
  k_prep_x<<<dim3(KT1 * 2, NTOK / 128), 256, 0, stream>>>(x, q1, a1s);

  k_gemm1<<<dim3(FFND / 128, NTOK / 256), 512, 0, stream>>>(
      q1, w1p, w3p, q2, w1s, w3s, a1s, a2s);
  k_gemm2<<<dim3(HID / 256, NTOK / 256), 256, 0, stream>>>(
      q2, w2p, out, w2s, a2s);
}

// Round 18
// 1583.430 us; speedup vs baseline: 1.1017x; 1.1017x over previous
//
#include <hip/hip_runtime.h>
#include <math.h>
#include <stdint.h>

typedef int v4i  __attribute__((ext_vector_type(4)));
typedef int v16i __attribute__((ext_vector_type(16)));

#define NTOK 8192
#define HID  4096
#define FFND 14336

typedef const __attribute__((address_space(1))) void* gp_t;
typedef __attribute__((address_space(3))) void*       lp_t;

#define BAR()      __builtin_amdgcn_s_barrier()
#define SETPRIO(p) __builtin_amdgcn_s_setprio(p)
#define MEMFENCE() asm volatile("" ::: "memory")

// ---- fused prep: pack w1/w3/w2 (int32->int8) + quantize x, one dispatch ----
// blockIdx.y: 0=w1 1=w3 2=w2 (wn4 int4-groups), 3=quant x (n4 float4-groups)
__global__ __launch_bounds__(256) void k_prep(
    const int* __restrict__ w1, const int* __restrict__ w3,
    const int* __restrict__ w2, const float* __restrict__ x,
    int8_t* __restrict__ o1, int8_t* __restrict__ o3,
    int8_t* __restrict__ o2, int8_t* __restrict__ qx,
    const float* __restrict__ a1sp, int wn4, int n4) {
  int i = blockIdx.x * 256 + threadIdx.x;
  if (blockIdx.y == 3) {
    if (i >= n4) return;
    float s = *a1sp;
    float4 v = reinterpret_cast<const float4*>(x)[i];
    int a = (int)rintf(v.x / s); a = a < -128 ? -128 : (a > 127 ? 127 : a);
    int b = (int)rintf(v.y / s); b = b < -128 ? -128 : (b > 127 ? 127 : b);
    int c = (int)rintf(v.z / s); c = c < -128 ? -128 : (c > 127 ? 127 : c);
    int d = (int)rintf(v.w / s); d = d < -128 ? -128 : (d > 127 ? 127 : d);
    reinterpret_cast<int*>(qx)[i] =
        (a & 255) | ((b & 255) << 8) | ((c & 255) << 16) | ((d & 255) << 24);
    return;
  }
  if (i >= wn4) return;
  const int* s = (blockIdx.y == 0) ? w1 : (blockIdx.y == 1) ? w3 : w2;
  int8_t*    d = (blockIdx.y == 0) ? o1 : (blockIdx.y == 1) ? o3 : o2;
  int4 v = reinterpret_cast<const int4*>(s)[i];
  reinterpret_cast<int*>(d)[i] =
      (v.x & 255) | ((v.y & 255) << 8) | ((v.z & 255) << 16) | ((v.w & 255) << 24);
}

// ---- stage one [ROWS][64B] int8 tile into LDS (XOR-swizzled, rule #21) ----
template <int ROWS, int NWAVES>
__device__ __forceinline__ void stage_tile(const int8_t* __restrict__ src,
                                           int ld, int8_t* lds,
                                           int wave, int lane) {
  constexpr int NSEG = ROWS / 16;
  constexpr int PER  = NSEG / NWAVES;
#pragma unroll
  for (int j = 0; j < PER; ++j) {
    const int seg  = wave * PER + j;
    const int o    = (seg << 10) + (lane << 4);
    const int row  = o >> 6;
    const int slot = (o >> 4) & 3;
    const int gs   = slot ^ ((row >> 1) & 3);
    const int8_t* g = src + (size_t)row * ld + (gs << 4);
    __builtin_amdgcn_global_load_lds((gp_t)g, (lp_t)(lds + (seg << 10)), 16, 0, 0);
  }
}

// read one 16B MFMA fragment (row, linear k-slot) with the inverse swizzle
__device__ __forceinline__ v4i frag16(const int8_t* lds, int row, int sl) {
  const int s2 = sl ^ ((row >> 1) & 3);
  return *reinterpret_cast<const v4i*>(lds + (row << 6) + (s2 << 4));
}

// ------- GEMM1 (champion: ~945us @ MfmaUtil 51%) -------
// 512 thr / 8 waves; tile 256x128 dual (gate+up); depth-3, 96 KiB, 1 block/CU.
// Per K-tile: vmcnt(4) -> BAR -> reads(12) -> stage(kt+2) -> setprio MFMA.
__global__ __launch_bounds__(512, 2) void k_gemm1(
    const int8_t* __restrict__ q1, const int8_t* __restrict__ w1,
    const int8_t* __restrict__ w3, int8_t* __restrict__ q2,
    const float* __restrict__ w1sp, const float* __restrict__ w3sp,
    const float* __restrict__ a1sp, const float* __restrict__ a2sp) {
  __shared__ __align__(16) int8_t As[3][256 * 64];   // 48 KiB
  __shared__ __align__(16) int8_t B1s[3][128 * 64];  // 24 KiB
  __shared__ __align__(16) int8_t B3s[3][128 * 64];  // 24 KiB
  const int lane = threadIdx.x & 63;
  const int wave = threadIdx.x >> 6;   // 0..7
  const int wr = wave >> 1;            // 0..3 (M quadrant, 64 rows)
  const int wc = wave & 1;             // 0..1 (N half, 64 cols)
  const int r0 = lane & 31;
  const int mbase = blockIdx.y * 256;
  const int nbase = blockIdx.x * 128;
  const int8_t* Ap  = q1 + (size_t)mbase * HID;
  const int8_t* B1p = w1 + (size_t)nbase * HID;
  const int8_t* B3p = w3 + (size_t)nbase * HID;
  constexpr int NT = HID / 64;

  v16i acc1[2][2], acc3[2][2];
#pragma unroll
  for (int m = 0; m < 2; ++m)
#pragma unroll
    for (int n = 0; n < 2; ++n)
#pragma unroll
      for (int r = 0; r < 16; ++r) { acc1[m][n][r] = 0; acc3[m][n][r] = 0; }

#pragma unroll
  for (int t = 0; t < 2; ++t) {
    stage_tile<256, 8>(Ap  + t * 64, HID, As[t],  wave, lane);
    stage_tile<128, 8>(B1p + t * 64, HID, B1s[t], wave, lane);
    stage_tile<128, 8>(B3p + t * 64, HID, B3s[t], wave, lane);
  }

  int cur = 0;
  for (int kt = 0; kt < NT; ++kt) {
    if (kt < NT - 1) asm volatile("s_waitcnt vmcnt(4)" ::: "memory");
    else             asm volatile("s_waitcnt vmcnt(0)" ::: "memory");
    BAR();
    MEMFENCE();
    const int8_t* Ac  = As[cur];
    const int8_t* B1c = B1s[cur];
    const int8_t* B3c = B3s[cur];
    v4i a[2][2], b1[2][2], b3[2][2];
#pragma unroll
    for (int kk = 0; kk < 2; ++kk) {
      const int sl = kk * 2 + (lane >> 5);
      a[kk][0]  = frag16(Ac,  wr * 64 +      r0, sl);
      a[kk][1]  = frag16(Ac,  wr * 64 + 32 + r0, sl);
      b1[kk][0] = frag16(B1c, wc * 64 +      r0, sl);
      b1[kk][1] = frag16(B1c, wc * 64 + 32 + r0, sl);
      b3[kk][0] = frag16(B3c, wc * 64 +      r0, sl);
      b3[kk][1] = frag16(B3c, wc * 64 + 32 + r0, sl);
    }
    const int nx2 = (cur >= 1) ? cur - 1 : 2;
    if (kt + 2 < NT) {
      stage_tile<256, 8>(Ap  + (kt + 2) * 64, HID, As[nx2],  wave, lane);
      stage_tile<128, 8>(B1p + (kt + 2) * 64, HID, B1s[nx2], wave, lane);
      stage_tile<128, 8>(B3p + (kt + 2) * 64, HID, B3s[nx2], wave, lane);
    }
    SETPRIO(1);
#pragma unroll
    for (int kk = 0; kk < 2; ++kk)
#pragma unroll
      for (int m = 0; m < 2; ++m)
#pragma unroll
        for (int n = 0; n < 2; ++n) {
          acc1[m][n] = __builtin_amdgcn_mfma_i32_32x32x32_i8(a[kk][m], b1[kk][n], acc1[m][n], 0, 0, 0);
          acc3[m][n] = __builtin_amdgcn_mfma_i32_32x32x32_i8(a[kk][m], b3[kk][n], acc3[m][n], 0, 0, 0);
        }
    SETPRIO(0);
    cur = (cur == 2) ? 0 : cur + 1;
  }

  const float s1 = (*a1sp) * (*w1sp);
  const float s3 = (*a1sp) * (*w3sp);
  const float ia2 = 1.f / (*a2sp);
#pragma unroll
  for (int m = 0; m < 2; ++m)
#pragma unroll
    for (int n = 0; n < 2; ++n) {
      const int colg = nbase + wc * 64 + n * 32 + r0;
#pragma unroll
      for (int r = 0; r < 16; ++r) {
        const int rowg = mbase + wr * 64 + m * 32 +
                         (r & 3) + ((r >> 2) << 3) + ((lane >> 5) << 2);
        const float g = (float)acc1[m][n][r] * s1;
        const float u = (float)acc3[m][n][r] * s3;
        const float h = g * __builtin_amdgcn_rcpf(1.f + __expf(-g)) * u;
        float t = rintf(h * ia2);
        t = fminf(fmaxf(t, -128.f), 127.f);
        q2[(size_t)rowg * FFND + colg] = (int8_t)(int)t;
      }
    }
}

// ------- GEMM2 (champion: big-acc, A/B-verified vs phase variant) -------
// 256 thr / 4 waves (1 wave/SIMD); block 256x256; per-wave 128x128
// (acc 256 AGPR); depth-3 (96 KiB); vmcnt(8); reads -> stage -> setprio MFMA.
__global__ __launch_bounds__(256, 1) void k_gemm2(
    const int8_t* __restrict__ q2, const int8_t* __restrict__ w2,
    float* __restrict__ out,
    const float* __restrict__ w2sp, const float* __restrict__ a2sp) {
  __shared__ __align__(16) int8_t As[3][256 * 64];  // 48 KiB
  __shared__ __align__(16) int8_t Bs[3][256 * 64];  // 48 KiB
  const int lane = threadIdx.x & 63;
  const int wave = threadIdx.x >> 6;   // 0..3
  const int wr = wave >> 1;            // 0..1 (M half, 128 rows)
  const int wc = wave & 1;             // 0..1 (N half, 128 cols)
  const int r0 = lane & 31;
  const int mbase = blockIdx.y * 256;
  const int nbase = blockIdx.x * 256;
  const int8_t* Ap = q2 + (size_t)mbase * FFND;
  const int8_t* Bp = w2 + (size_t)nbase * FFND;
  constexpr int NT = FFND / 64;

  v16i acc[4][4];
#pragma unroll
  for (int m = 0; m < 4; ++m)
#pragma unroll
    for (int n = 0; n < 4; ++n)
#pragma unroll
      for (int r = 0; r < 16; ++r) acc[m][n][r] = 0;

#pragma unroll
  for (int t = 0; t < 2; ++t) {
    stage_tile<256, 4>(Ap + t * 64, FFND, As[t], wave, lane);
    stage_tile<256, 4>(Bp + t * 64, FFND, Bs[t], wave, lane);
  }

  int cur = 0;
  for (int kt = 0; kt < NT; ++kt) {
    if (kt < NT - 1) asm volatile("s_waitcnt vmcnt(8)" ::: "memory");
    else             asm volatile("s_waitcnt vmcnt(0)" ::: "memory");
    BAR();
    MEMFENCE();
    const int8_t* Ac = As[cur];
    const int8_t* Bc = Bs[cur];
    v4i a[2][4], b[2][4];
#pragma unroll
    for (int kk = 0; kk < 2; ++kk) {
      const int sl = kk * 2 + (lane >> 5);
#pragma unroll
      for (int m = 0; m < 4; ++m)
        a[kk][m] = frag16(Ac, wr * 128 + m * 32 + r0, sl);
#pragma unroll
      for (int n = 0; n < 4; ++n)
        b[kk][n] = frag16(Bc, wc * 128 + n * 32 + r0, sl);
    }
    const int nx2 = (cur >= 1) ? cur - 1 : 2;
    if (kt + 2 < NT) {
      stage_tile<256, 4>(Ap + (kt + 2) * 64, FFND, As[nx2], wave, lane);
      stage_tile<256, 4>(Bp + (kt + 2) * 64, FFND, Bs[nx2], wave, lane);
    }
    SETPRIO(1);
#pragma unroll
    for (int kk = 0; kk < 2; ++kk)
#pragma unroll
      for (int m = 0; m < 4; ++m)
#pragma unroll
        for (int n = 0; n < 4; ++n)
          acc[m][n] = __builtin_amdgcn_mfma_i32_32x32x32_i8(a[kk][m], b[kk][n], acc[m][n], 0, 0, 0);
    SETPRIO(0);
    cur = (cur == 2) ? 0 : cur + 1;
  }

  const float s = (*a2sp) * (*w2sp);
#pragma unroll
  for (int m = 0; m < 4; ++m)
#pragma unroll
    for (int n = 0; n < 4; ++n) {
      const int colg = nbase + wc * 128 + n * 32 + r0;
#pragma unroll
      for (int r = 0; r < 16; ++r) {
        const int rowg = mbase + wr * 128 + m * 32 +
                         (r & 3) + ((r >> 2) << 3) + ((lane >> 5) << 2);
        out[(size_t)rowg * HID + colg] = (float)acc[m][n][r] * s;
      }
    }
}

extern "C" void kernel_launch(void* const* d_in, const int* in_sizes, int n_in,
                              void* d_out, int out_size, void* d_ws, size_t ws_size,
                              hipStream_t stream) {
  const float* x    = (const float*)d_in[0];
  const int*   w1i  = (const int*)d_in[1];   // int8 values stored as int32
  const int*   w3i  = (const int*)d_in[2];
  const int*   w2i  = (const int*)d_in[3];
  const float* w1s  = (const float*)d_in[4];
  const float* w3s  = (const float*)d_in[5];
  const float* w2s  = (const float*)d_in[6];
  const float* a1s  = (const float*)d_in[7];
  const float* a2s  = (const float*)d_in[8];
  float* out = (float*)d_out;

  // workspace layout
  int8_t* q1  = (int8_t*)d_ws;                         // [NTOK][HID]    33.5 MB
  int8_t* q2  = q1 + (size_t)NTOK * HID;               // [NTOK][FFND]  117.4 MB
  int8_t* w1p = q2 + (size_t)NTOK * FFND;              // [FFN][HID]     58.7 MB
  int8_t* w3p = w1p + (size_t)FFND * HID;              //                58.7 MB
  int8_t* w2p = w3p + (size_t)FFND * HID;              // [HID][FFN]     58.7 MB

  const int wn4 = (int)((size_t)FFND * HID / 4);       // 14,680,064
  const int n4  = NTOK * HID / 4;                      //  8,388,608
  k_prep<<<dim3(wn4 / 256, 4), 256, 0, stream>>>(
      w1i, w3i, w2i, x, w1p, w3p, w2p, q1, a1s, wn4, n4);

  k_gemm1<<<dim3(FFND / 128, NTOK / 256), 512, 0, stream>>>(
      q1, w1p, w3p, q2, w1s, w3s, a1s, a2s);
  k_gemm2<<<dim3(HID / 256, NTOK / 256), 256, 0, stream>>>(
      q2, w2p, out, w2s, a2s);
}

// Round 20
// 1540.429 us; speedup vs baseline: 1.1325x; 1.0279x over previous
//
#include <hip/hip_runtime.h>
#include <math.h>
#include <stdint.h>

typedef int v4i  __attribute__((ext_vector_type(4)));
typedef int v16i __attribute__((ext_vector_type(16)));

#define NTOK 8192
#define HID  4096
#define FFND 14336

typedef const __attribute__((address_space(1))) void* gp_t;
typedef __attribute__((address_space(3))) void*       lp_t;

#define BAR()      __builtin_amdgcn_s_barrier()
#define SETPRIO(p) __builtin_amdgcn_s_setprio(p)
#define MEMFENCE() asm volatile("" ::: "memory")

// ---- fused prep: pack w1/w3/w2 (int32->int8) + quantize x, one dispatch ----
// blockIdx.y: 0=w1 1=w3 2=w2 (wn4 int4-groups), 3=quant x (n4 float4-groups)
__global__ __launch_bounds__(256) void k_prep(
    const int* __restrict__ w1, const int* __restrict__ w3,
    const int* __restrict__ w2, const float* __restrict__ x,
    int8_t* __restrict__ o1, int8_t* __restrict__ o3,
    int8_t* __restrict__ o2, int8_t* __restrict__ qx,
    const float* __restrict__ a1sp, int wn4, int n4) {
  int i = blockIdx.x * 256 + threadIdx.x;
  if (blockIdx.y == 3) {
    if (i >= n4) return;
    float s = *a1sp;
    float4 v = reinterpret_cast<const float4*>(x)[i];
    int a = (int)rintf(v.x / s); a = a < -128 ? -128 : (a > 127 ? 127 : a);
    int b = (int)rintf(v.y / s); b = b < -128 ? -128 : (b > 127 ? 127 : b);
    int c = (int)rintf(v.z / s); c = c < -128 ? -128 : (c > 127 ? 127 : c);
    int d = (int)rintf(v.w / s); d = d < -128 ? -128 : (d > 127 ? 127 : d);
    reinterpret_cast<int*>(qx)[i] =
        (a & 255) | ((b & 255) << 8) | ((c & 255) << 16) | ((d & 255) << 24);
    return;
  }
  if (i >= wn4) return;
  const int* s = (blockIdx.y == 0) ? w1 : (blockIdx.y == 1) ? w3 : w2;
  int8_t*    d = (blockIdx.y == 0) ? o1 : (blockIdx.y == 1) ? o3 : o2;
  int4 v = reinterpret_cast<const int4*>(s)[i];
  reinterpret_cast<int*>(d)[i] =
      (v.x & 255) | ((v.y & 255) << 8) | ((v.z & 255) << 16) | ((v.w & 255) << 24);
}

// ---- stage one [ROWS][64B] int8 tile into LDS (XOR-swizzled, rule #21) ----
template <int ROWS, int NWAVES>
__device__ __forceinline__ void stage_tile(const int8_t* __restrict__ src,
                                           int ld, int8_t* lds,
                                           int wave, int lane) {
  constexpr int NSEG = ROWS / 16;
  constexpr int PER  = NSEG / NWAVES;
#pragma unroll
  for (int j = 0; j < PER; ++j) {
    const int seg  = wave * PER + j;
    const int o    = (seg << 10) + (lane << 4);
    const int row  = o >> 6;
    const int slot = (o >> 4) & 3;
    const int gs   = slot ^ ((row >> 1) & 3);
    const int8_t* g = src + (size_t)row * ld + (gs << 4);
    __builtin_amdgcn_global_load_lds((gp_t)g, (lp_t)(lds + (seg << 10)), 16, 0, 0);
  }
}

// read one 16B MFMA fragment (row, linear k-slot) with the inverse swizzle
__device__ __forceinline__ v4i frag16(const int8_t* lds, int row, int sl) {
  const int s2 = sl ^ ((row >> 1) & 3);
  return *reinterpret_cast<const v4i*>(lds + (row << 6) + (s2 << 4));
}

// ------- GEMM1 (champion, unchanged: ~945us @ MfmaUtil 51%) -------
// 512 thr / 8 waves; tile 256x128 dual (gate+up); depth-3, 96 KiB, 1 block/CU.
// Per K-tile: vmcnt(4) -> BAR -> reads(12) -> stage(kt+2) -> setprio MFMA.
__global__ __launch_bounds__(512, 2) void k_gemm1(
    const int8_t* __restrict__ q1, const int8_t* __restrict__ w1,
    const int8_t* __restrict__ w3, int8_t* __restrict__ q2,
    const float* __restrict__ w1sp, const float* __restrict__ w3sp,
    const float* __restrict__ a1sp, const float* __restrict__ a2sp) {
  __shared__ __align__(16) int8_t As[3][256 * 64];   // 48 KiB
  __shared__ __align__(16) int8_t B1s[3][128 * 64];  // 24 KiB
  __shared__ __align__(16) int8_t B3s[3][128 * 64];  // 24 KiB
  const int lane = threadIdx.x & 63;
  const int wave = threadIdx.x >> 6;   // 0..7
  const int wr = wave >> 1;            // 0..3 (M quadrant, 64 rows)
  const int wc = wave & 1;             // 0..1 (N half, 64 cols)
  const int r0 = lane & 31;
  const int mbase = blockIdx.y * 256;
  const int nbase = blockIdx.x * 128;
  const int8_t* Ap  = q1 + (size_t)mbase * HID;
  const int8_t* B1p = w1 + (size_t)nbase * HID;
  const int8_t* B3p = w3 + (size_t)nbase * HID;
  constexpr int NT = HID / 64;

  v16i acc1[2][2], acc3[2][2];
#pragma unroll
  for (int m = 0; m < 2; ++m)
#pragma unroll
    for (int n = 0; n < 2; ++n)
#pragma unroll
      for (int r = 0; r < 16; ++r) { acc1[m][n][r] = 0; acc3[m][n][r] = 0; }

#pragma unroll
  for (int t = 0; t < 2; ++t) {
    stage_tile<256, 8>(Ap  + t * 64, HID, As[t],  wave, lane);
    stage_tile<128, 8>(B1p + t * 64, HID, B1s[t], wave, lane);
    stage_tile<128, 8>(B3p + t * 64, HID, B3s[t], wave, lane);
  }

  int cur = 0;
  for (int kt = 0; kt < NT; ++kt) {
    if (kt < NT - 1) asm volatile("s_waitcnt vmcnt(4)" ::: "memory");
    else             asm volatile("s_waitcnt vmcnt(0)" ::: "memory");
    BAR();
    MEMFENCE();
    const int8_t* Ac  = As[cur];
    const int8_t* B1c = B1s[cur];
    const int8_t* B3c = B3s[cur];
    v4i a[2][2], b1[2][2], b3[2][2];
#pragma unroll
    for (int kk = 0; kk < 2; ++kk) {
      const int sl = kk * 2 + (lane >> 5);
      a[kk][0]  = frag16(Ac,  wr * 64 +      r0, sl);
      a[kk][1]  = frag16(Ac,  wr * 64 + 32 + r0, sl);
      b1[kk][0] = frag16(B1c, wc * 64 +      r0, sl);
      b1[kk][1] = frag16(B1c, wc * 64 + 32 + r0, sl);
      b3[kk][0] = frag16(B3c, wc * 64 +      r0, sl);
      b3[kk][1] = frag16(B3c, wc * 64 + 32 + r0, sl);
    }
    const int nx2 = (cur >= 1) ? cur - 1 : 2;
    if (kt + 2 < NT) {
      stage_tile<256, 8>(Ap  + (kt + 2) * 64, HID, As[nx2],  wave, lane);
      stage_tile<128, 8>(B1p + (kt + 2) * 64, HID, B1s[nx2], wave, lane);
      stage_tile<128, 8>(B3p + (kt + 2) * 64, HID, B3s[nx2], wave, lane);
    }
    SETPRIO(1);
#pragma unroll
    for (int kk = 0; kk < 2; ++kk)
#pragma unroll
      for (int m = 0; m < 2; ++m)
#pragma unroll
        for (int n = 0; n < 2; ++n) {
          acc1[m][n] = __builtin_amdgcn_mfma_i32_32x32x32_i8(a[kk][m], b1[kk][n], acc1[m][n], 0, 0, 0);
          acc3[m][n] = __builtin_amdgcn_mfma_i32_32x32x32_i8(a[kk][m], b3[kk][n], acc3[m][n], 0, 0, 0);
        }
    SETPRIO(0);
    cur = (cur == 2) ? 0 : cur + 1;
  }

  const float s1 = (*a1sp) * (*w1sp);
  const float s3 = (*a1sp) * (*w3sp);
  const float ia2 = 1.f / (*a2sp);
#pragma unroll
  for (int m = 0; m < 2; ++m)
#pragma unroll
    for (int n = 0; n < 2; ++n) {
      const int colg = nbase + wc * 64 + n * 32 + r0;
#pragma unroll
      for (int r = 0; r < 16; ++r) {
        const int rowg = mbase + wr * 64 + m * 32 +
                         (r & 3) + ((r >> 2) << 3) + ((lane >> 5) << 2);
        const float g = (float)acc1[m][n][r] * s1;
        const float u = (float)acc3[m][n][r] * s3;
        const float h = g * __builtin_amdgcn_rcpf(1.f + __expf(-g)) * u;
        float t = rintf(h * ia2);
        t = fminf(fmaxf(t, -128.f), 127.f);
        q2[(size_t)rowg * FFND + colg] = (int8_t)(int)t;
      }
    }
}

// ------- GEMM2: gemm1's winning recipe ported (single-variable change) -------
// 512 thr / 8 waves (4M x 2N, 2 waves/SIMD); tile 256x256; per-wave 64x128
// (acc[2][4] = 128 AGPR); depth-3 (96 KiB), 1 block/CU; counted vmcnt(4);
// free-scheduled region: reads(12) -> stage(kt+2) -> setprio MFMA(16).
__global__ __launch_bounds__(512, 2) void k_gemm2(
    const int8_t* __restrict__ q2, const int8_t* __restrict__ w2,
    float* __restrict__ out,
    const float* __restrict__ w2sp, const float* __restrict__ a2sp) {
  __shared__ __align__(16) int8_t As[3][256 * 64];  // 48 KiB
  __shared__ __align__(16) int8_t Bs[3][256 * 64];  // 48 KiB
  const int lane = threadIdx.x & 63;
  const int wave = threadIdx.x >> 6;   // 0..7
  const int wr = wave >> 1;            // 0..3 (M quadrant, 64 rows)
  const int wc = wave & 1;             // 0..1 (N half, 128 cols)
  const int r0 = lane & 31;
  const int mbase = blockIdx.y * 256;
  const int nbase = blockIdx.x * 256;
  const int8_t* Ap = q2 + (size_t)mbase * FFND;
  const int8_t* Bp = w2 + (size_t)nbase * FFND;
  constexpr int NT = FFND / 64;

  v16i acc[2][4];
#pragma unroll
  for (int m = 0; m < 2; ++m)
#pragma unroll
    for (int n = 0; n < 4; ++n)
#pragma unroll
      for (int r = 0; r < 16; ++r) acc[m][n][r] = 0;

#pragma unroll
  for (int t = 0; t < 2; ++t) {
    stage_tile<256, 8>(Ap + t * 64, FFND, As[t], wave, lane);
    stage_tile<256, 8>(Bp + t * 64, FFND, Bs[t], wave, lane);
  }

  int cur = 0;
  for (int kt = 0; kt < NT; ++kt) {
    if (kt < NT - 1) asm volatile("s_waitcnt vmcnt(4)" ::: "memory");
    else             asm volatile("s_waitcnt vmcnt(0)" ::: "memory");
    BAR();
    MEMFENCE();
    const int8_t* Ac = As[cur];
    const int8_t* Bc = Bs[cur];
    v4i a[2][2], b[2][4];
#pragma unroll
    for (int kk = 0; kk < 2; ++kk) {
      const int sl = kk * 2 + (lane >> 5);
      a[kk][0] = frag16(Ac, wr * 64 +      r0, sl);
      a[kk][1] = frag16(Ac, wr * 64 + 32 + r0, sl);
#pragma unroll
      for (int n = 0; n < 4; ++n)
        b[kk][n] = frag16(Bc, wc * 128 + n * 32 + r0, sl);
    }
    const int nx2 = (cur >= 1) ? cur - 1 : 2;
    if (kt + 2 < NT) {
      stage_tile<256, 8>(Ap + (kt + 2) * 64, FFND, As[nx2], wave, lane);
      stage_tile<256, 8>(Bp + (kt + 2) * 64, FFND, Bs[nx2], wave, lane);
    }
    SETPRIO(1);
#pragma unroll
    for (int kk = 0; kk < 2; ++kk)
#pragma unroll
      for (int m = 0; m < 2; ++m)
#pragma unroll
        for (int n = 0; n < 4; ++n)
          acc[m][n] = __builtin_amdgcn_mfma_i32_32x32x32_i8(a[kk][m], b[kk][n], acc[m][n], 0, 0, 0);
    SETPRIO(0);
    cur = (cur == 2) ? 0 : cur + 1;
  }

  const float s = (*a2sp) * (*w2sp);
#pragma unroll
  for (int m = 0; m < 2; ++m)
#pragma unroll
    for (int n = 0; n < 4; ++n) {
      const int colg = nbase + wc * 128 + n * 32 + r0;
#pragma unroll
      for (int r = 0; r < 16; ++r) {
        const int rowg = mbase + wr * 64 + m * 32 +
                         (r & 3) + ((r >> 2) << 3) + ((lane >> 5) << 2);
        out[(size_t)rowg * HID + colg] = (float)acc[m][n][r] * s;
      }
    }
}

extern "C" void kernel_launch(void* const* d_in, const int* in_sizes, int n_in,
                              void* d_out, int out_size, void* d_ws, size_t ws_size,
                              hipStream_t stream) {
  const float* x    = (const float*)d_in[0];
  const int*   w1i  = (const int*)d_in[1];   // int8 values stored as int32
  const int*   w3i  = (const int*)d_in[2];
  const int*   w2i  = (const int*)d_in[3];
  const float* w1s  = (const float*)d_in[4];
  const float* w3s  = (const float*)d_in[5];
  const float* w2s  = (const float*)d_in[6];
  const float* a1s  = (const float*)d_in[7];
  const float* a2s  = (const float*)d_in[8];
  float* out = (float*)d_out;

  // workspace layout
  int8_t* q1  = (int8_t*)d_ws;                         // [NTOK][HID]    33.5 MB
  int8_t* q2  = q1 + (size_t)NTOK * HID;               // [NTOK][FFND]  117.4 MB
  int8_t* w1p = q2 + (size_t)NTOK * FFND;              // [FFN][HID]     58.7 MB
  int8_t* w3p = w1p + (size_t)FFND * HID;              //                58.7 MB
  int8_t* w2p = w3p + (size_t)FFND * HID;              // [HID][FFN]     58.7 MB

  const int wn4 = (int)((size_t)FFND * HID / 4);       // 14,680,064
  const int n4  = NTOK * HID / 4;                      //  8,388,608
  k_prep<<<dim3(wn4 / 256, 4), 256, 0, stream>>>(
      w1i, w3i, w2i, x, w1p, w3p, w2p, q1, a1s, wn4, n4);

  k_gemm1<<<dim3(FFND / 128, NTOK / 256), 512, 0, stream>>>(
      q1, w1p, w3p, q2, w1s, w3s, a1s, a2s);
  k_gemm2<<<dim3(HID / 256, NTOK / 256), 512, 0, stream>>>(
      q2, w2p, out, w2s, a2s);
}